// Round 13
// baseline (548.962 us; speedup 1.0000x reference)
//
#include <hip/hip_runtime.h>

// AttackLSTM R28 — 2 batch elements per block (interleaved serial chains).
// R27 post-mortem: 265us, all counters clean (WRITE 512KB, conflicts 1e6,
// MfmaUtil 38%). Step = 1240cy vs ~500cy static chain -> latency-bound with
// bubbles that single-element code cannot fill (h(t)->h(t+1) serial).
// R28: grid 128 blocks x 2 elements; every wave processes both elements per
// step. Independent chains interleave: 2 A-loads overlap, 64 MFMAs
// back-to-back, dual gate chains ILP. Weights SHARED (bfr loaded once).
// Acc liveness capped by gate-grouping (8 tiles live, sched_barrier) so
// rec arch ~100 < 128 (full 2x acc[16] would spill). LDS ~85KB (2x rings).
// Sync protocol identical: prog[6], one POSTP/window for both elements.
// Verify: WRITE ~512KB, dur 150-200us, absmax=0.

#define NB 128  // blocks; each handles 2 batch elements
#define TT 512
#define CH 4
#define NS 16  // ring slots -> 4-window slack
#define NW (TT / CH)
#define HP 72   // padded hh row (halfs): 144B
#define PP 260  // padded pj row (floats): 1040B

typedef _Float16 v2h __attribute__((ext_vector_type(2)));
typedef _Float16 v8h __attribute__((ext_vector_type(8)));
typedef float v4f __attribute__((ext_vector_type(4)));

__device__ __forceinline__ float sig_(float x) {
  return __builtin_amdgcn_rcpf(1.f + __builtin_amdgcn_exp2f(-1.44269504f * x));
}
__device__ __forceinline__ float tanh_(float x) {
  return __builtin_fmaf(2.f, __builtin_amdgcn_rcpf(1.f + __builtin_amdgcn_exp2f(-2.88539008f * x)), -1.f);
}

template <int K>
__device__ __forceinline__ float qb_(float v) {
  return __int_as_float(__builtin_amdgcn_update_dpp(
      0, __float_as_int(v), (K | (K << 2) | (K << 4) | (K << 6)), 0xF, 0xF, true));
}

#if __has_builtin(__builtin_amdgcn_fdot2)
#define FDOT2(acc, a, b) (acc) = __builtin_amdgcn_fdot2((a), (b), (acc), false)
#else
#define FDOT2(acc, a, b) \
  (acc) = __builtin_fmaf((float)(a)[0], (float)(b)[0], \
          __builtin_fmaf((float)(a)[1], (float)(b)[1], (acc)))
#endif
#define KEEPP(a) asm volatile("" : "+v"(a))
#define PIN16(w)                                                            \
  do {                                                                      \
    _Pragma("unroll") for (int _i = 0; _i < 16; ++_i) KEEPP((w)[_i]);       \
  } while (0)

// Spin until prog[i] >= v (acquire), sleeping between polls.
#define WAITP(i, v)                                                           \
  while (__hip_atomic_load(&prog[i], __ATOMIC_ACQUIRE,                        \
                           __HIP_MEMORY_SCOPE_WORKGROUP) < (v)) {             \
    __builtin_amdgcn_s_sleep(1);                                              \
  }
// Publish prog[i] = v after all this wave's data ds_writes retired.
#define POSTP(i, v)                                                           \
  do {                                                                        \
    asm volatile("s_waitcnt lgkmcnt(0)" ::: "memory");                        \
    if (lane == 0)                                                            \
      __hip_atomic_store(&prog[i], (v), __ATOMIC_RELEASE,                     \
                         __HIP_MEMORY_SCOPE_WORKGROUP);                       \
  } while (0)

__device__ __forceinline__ v2h bc2h_(int v) { return __builtin_bit_cast(v2h, v); }

// 64 halfs from LDS as 32 v2h via int4 reads (8x ds_read_b128, broadcast).
__device__ __forceinline__ void load_h64(const _Float16* p, v2h hv[32]) {
  const int4* hp = reinterpret_cast<const int4*>(p);
#pragma unroll
  for (int i = 0; i < 8; ++i) {
    int4 blk = hp[i];
    hv[4 * i + 0] = bc2h_(blk.x);
    hv[4 * i + 1] = bc2h_(blk.y);
    hv[4 * i + 2] = bc2h_(blk.z);
    hv[4 * i + 3] = bc2h_(blk.w);
  }
}

// fp32 row of 64 -> two 16-v2h halves (b-chain).
__device__ __forceinline__ void load_row_pair(const float* src, v2h* lo, v2h* hi) {
  const float4* p = reinterpret_cast<const float4*>(src);
#pragma unroll
  for (int i = 0; i < 8; ++i) {
    float4 v = p[i];
    lo[2 * i]     = v2h{(_Float16)v.x, (_Float16)v.y};
    lo[2 * i + 1] = v2h{(_Float16)v.z, (_Float16)v.w};
  }
#pragma unroll
  for (int i = 0; i < 8; ++i) {
    float4 v = p[8 + i];
    hi[2 * i]     = v2h{(_Float16)v.x, (_Float16)v.y};
    hi[2 * i + 1] = v2h{(_Float16)v.z, (_Float16)v.w};
  }
}

// W-fragment for tile t, K-chunk kc of W[256x64] row-major f32 (validated).
__device__ __forceinline__ v8h ldbfrag_(const float* W, int t, int kc, int lane) {
  const int row = 16 * t + (lane & 15);
  const float* p = W + row * 64 + 32 * kc + 4 * (lane >> 4);
  float4 fa = *reinterpret_cast<const float4*>(p);
  float4 fb = *reinterpret_cast<const float4*>(p + 16);
  return v8h{(_Float16)fa.x, (_Float16)fa.y, (_Float16)fa.z, (_Float16)fa.w,
             (_Float16)fb.x, (_Float16)fb.y, (_Float16)fb.z, (_Float16)fb.w};
}

// A-fragment pair (validated layout) from an hh slot.
__device__ __forceinline__ void ldafrag_(const _Float16* hprev, int q4,
                                         v8h& A0, v8h& A1) {
  const char* hp = (const char*)hprev + 8 * q4;
  int2 r00 = *(const int2*)(hp);
  int2 r01 = *(const int2*)(hp + 32);
  int2 r10 = *(const int2*)(hp + 64);
  int2 r11 = *(const int2*)(hp + 96);
  A0 = __builtin_bit_cast(v8h, int4{r00.x, r00.y, r01.x, r01.y});
  A1 = __builtin_bit_cast(v8h, int4{r10.x, r10.y, r11.x, r11.y});
}

// Dual-element rec matvec: 64 MFMAs in 4 gate-groups (8 acc tiles live max).
__device__ __forceinline__ void rec_pair_(const v8h bfr[16][2],
                                          const v8h& A0, const v8h& A1,
                                          const v8h& B0, const v8h& B1,
                                          bool s0, bool s1,
                                          float p0[4], float p1[4]) {
  const v4f z = {0.f, 0.f, 0.f, 0.f};
#pragma unroll
  for (int g = 0; g < 4; ++g) {
    v4f xa0 = __builtin_amdgcn_mfma_f32_16x16x32_f16(A0, bfr[4 * g + 0][0], z, 0, 0, 0);
    xa0 = __builtin_amdgcn_mfma_f32_16x16x32_f16(A1, bfr[4 * g + 0][1], xa0, 0, 0, 0);
    v4f xa1 = __builtin_amdgcn_mfma_f32_16x16x32_f16(A0, bfr[4 * g + 1][0], z, 0, 0, 0);
    xa1 = __builtin_amdgcn_mfma_f32_16x16x32_f16(A1, bfr[4 * g + 1][1], xa1, 0, 0, 0);
    v4f xa2 = __builtin_amdgcn_mfma_f32_16x16x32_f16(A0, bfr[4 * g + 2][0], z, 0, 0, 0);
    xa2 = __builtin_amdgcn_mfma_f32_16x16x32_f16(A1, bfr[4 * g + 2][1], xa2, 0, 0, 0);
    v4f xa3 = __builtin_amdgcn_mfma_f32_16x16x32_f16(A0, bfr[4 * g + 3][0], z, 0, 0, 0);
    xa3 = __builtin_amdgcn_mfma_f32_16x16x32_f16(A1, bfr[4 * g + 3][1], xa3, 0, 0, 0);
    v4f ya0 = __builtin_amdgcn_mfma_f32_16x16x32_f16(B0, bfr[4 * g + 0][0], z, 0, 0, 0);
    ya0 = __builtin_amdgcn_mfma_f32_16x16x32_f16(B1, bfr[4 * g + 0][1], ya0, 0, 0, 0);
    v4f ya1 = __builtin_amdgcn_mfma_f32_16x16x32_f16(B0, bfr[4 * g + 1][0], z, 0, 0, 0);
    ya1 = __builtin_amdgcn_mfma_f32_16x16x32_f16(B1, bfr[4 * g + 1][1], ya1, 0, 0, 0);
    v4f ya2 = __builtin_amdgcn_mfma_f32_16x16x32_f16(B0, bfr[4 * g + 2][0], z, 0, 0, 0);
    ya2 = __builtin_amdgcn_mfma_f32_16x16x32_f16(B1, bfr[4 * g + 2][1], ya2, 0, 0, 0);
    v4f ya3 = __builtin_amdgcn_mfma_f32_16x16x32_f16(B0, bfr[4 * g + 3][0], z, 0, 0, 0);
    ya3 = __builtin_amdgcn_mfma_f32_16x16x32_f16(B1, bfr[4 * g + 3][1], ya3, 0, 0, 0);
    float v01 = s0 ? xa1[0] : xa0[0];
    float v23 = s0 ? xa3[0] : xa2[0];
    p0[g] = s1 ? v23 : v01;
    v01 = s0 ? ya1[0] : ya0[0];
    v23 = s0 ? ya3[0] : ya2[0];
    p1[g] = s1 ? v23 : v01;
    __builtin_amdgcn_sched_barrier(0);
  }
}

// Gate math for one element; returns h (bf: writes c in-place).
__device__ __forceinline__ float gates_(float p0, float p1, float p2, float p3,
                                        float& c) {
  float gi = sig_(p0), gf = sig_(p1), gg = tanh_(p2), go = sig_(p3);
  c = __builtin_fmaf(gf, c, gi * gg);
  return go * tanh_(c);
}

__global__ __attribute__((amdgpu_flat_work_group_size(384, 384),
                          amdgpu_waves_per_eu(2, 2)))
void lstm_pipe_k(
    const float* __restrict__ x,
    const float* __restrict__ wih_a0, const float* __restrict__ whh_a0,
    const float* __restrict__ bih_a0, const float* __restrict__ bhh_a0,
    const float* __restrict__ wih_a1, const float* __restrict__ whh_a1,
    const float* __restrict__ bih_a1, const float* __restrict__ bhh_a1,
    const float* __restrict__ wih_a2, const float* __restrict__ whh_a2,
    const float* __restrict__ bih_a2, const float* __restrict__ bhh_a2,
    const float* __restrict__ wih_b0, const float* __restrict__ whh_b0,
    const float* __restrict__ bih_b0, const float* __restrict__ bhh_b0,
    const float* __restrict__ wih_b1, const float* __restrict__ whh_b1,
    const float* __restrict__ bih_b1, const float* __restrict__ bhh_b1,
    const float* __restrict__ wih_b2, const float* __restrict__ whh_b2,
    const float* __restrict__ bih_b2, const float* __restrict__ bhh_b2,
    float* __restrict__ out)  // [B,T]
{
  const int b0 = 2 * blockIdx.x;  // this block's two batch elements
  const int tid = threadIdx.x;
  const int wave = tid >> 6;
  const int lane = tid & 63;

  __shared__ __align__(16) _Float16 hh[3][2][NS][HP];  // [layer][elem]
  __shared__ __align__(16) float pj[2][2][NS][PP];     // [proj][elem]
  __shared__ float xs[2 * TT];                         // [elem][t]
  __shared__ int prog[6];

  for (int i = tid; i < 2 * TT; i += 384) {
    const int e = i >> 9, t = i & (TT - 1);
    xs[i] = x[(size_t)(b0 + e) * TT + t];
  }
  for (int i = tid; i < 3 * 2 * NS * HP / 2; i += 384)
    reinterpret_cast<int*>(hh)[i] = 0;
  if (tid < 6) prog[tid] = 0;

  union UW {
    v8h bfr[16][2];
    v2h wtb[2][16];
  } u;

  float bias[4] = {0.f, 0.f, 0.f, 0.f};
  float wi0_[4] = {0.f, 0.f, 0.f, 0.f};
  float whb0[4] = {}, wi1b[4] = {}, wh1b[4] = {}, bb1[4] = {},
        wi2b[4] = {}, wh2b[4] = {}, bb2[4] = {};

  if (wave == 0) {
#pragma unroll
    for (int t = 0; t < 16; ++t) {
      u.bfr[t][0] = ldbfrag_(whh_a0, t, 0, lane);
      u.bfr[t][1] = ldbfrag_(whh_a0, t, 1, lane);
    }
#pragma unroll
    for (int q = 0; q < 4; ++q) {
      const int row = q * 64 + lane;
      bias[q] = bih_a0[row] + bhh_a0[row];
      wi0_[q] = wih_a0[row];
    }
  } else if (wave == 1) {
#pragma unroll
    for (int t = 0; t < 16; ++t) {
      u.bfr[t][0] = ldbfrag_(whh_a1, t, 0, lane);
      u.bfr[t][1] = ldbfrag_(whh_a1, t, 1, lane);
    }
#pragma unroll
    for (int q = 0; q < 4; ++q) bias[q] = bih_a1[q * 64 + lane] + bhh_a1[q * 64 + lane];
  } else if (wave == 2) {
#pragma unroll
    for (int t = 0; t < 16; ++t) {
      u.bfr[t][0] = ldbfrag_(whh_a2, t, 0, lane);
      u.bfr[t][1] = ldbfrag_(whh_a2, t, 1, lane);
    }
#pragma unroll
    for (int q = 0; q < 4; ++q) bias[q] = bih_a2[q * 64 + lane] + bhh_a2[q * 64 + lane];
  } else if (wave == 3) {
    const int q = lane & 3;
    load_row_pair(wih_b0 + q * 64, u.wtb[0], u.wtb[1]);
    bias[0] = bih_b0[q] + bhh_b0[q];
#pragma unroll
    for (int k = 0; k < 4; ++k) {
      whb0[k] = whh_b0[k];
      wi1b[k] = wih_b1[k]; wh1b[k] = whh_b1[k]; bb1[k] = bih_b1[k] + bhh_b1[k];
      wi2b[k] = wih_b2[k]; wh2b[k] = whh_b2[k]; bb2[k] = bih_b2[k] + bhh_b2[k];
    }
    PIN16(u.wtb[0]); PIN16(u.wtb[1]);
  } else if (wave == 4) {
#pragma unroll
    for (int t = 0; t < 16; ++t) {
      u.bfr[t][0] = ldbfrag_(wih_a1, t, 0, lane);
      u.bfr[t][1] = ldbfrag_(wih_a1, t, 1, lane);
    }
  } else {
#pragma unroll
    for (int t = 0; t < 16; ++t) {
      u.bfr[t][0] = ldbfrag_(wih_a2, t, 0, lane);
      u.bfr[t][1] = ldbfrag_(wih_a2, t, 1, lane);
    }
  }
  __syncthreads();

  float cA = 0.f, cB = 0.f;  // rec cell state for elem 0 / elem 1
  float h0bA = 0.f, c0bA = 0.f, h1bA = 0.f, c1bA = 0.f, h2bA = 0.f, c2bA = 0.f;
  float h0bB = 0.f, c0bB = 0.f, h1bB = 0.f, c1bB = 0.f, h2bB = 0.f, c2bB = 0.f;
  const int q4 = lane >> 4;
  const bool s0 = q4 & 1, s1 = q4 & 2;
  const v4f z = {0.f, 0.f, 0.f, 0.f};

  if (wave == 0) {  // a0 rec -> hh[0][*]; consumer w4
    __builtin_amdgcn_s_setprio(1);
    for (int k = 0; k < NW; ++k) {
      if (k >= 4) { WAITP(4, k - 3); }
      const int t0 = k * CH;
      for (int s = 0; s < CH; ++s) {
        const int t = t0 + s;
        const int sl = (t + NS - 1) & (NS - 1);
        v8h A0, A1, B0, B1;
        ldafrag_(&hh[0][0][sl][0], q4, A0, A1);
        ldafrag_(&hh[0][1][sl][0], q4, B0, B1);
        float p0[4], p1[4];
        rec_pair_(u.bfr, A0, A1, B0, B1, s0, s1, p0, p1);
        const float xv0 = xs[t], xv1 = xs[TT + t];
        float hA = gates_(__builtin_fmaf(wi0_[0], xv0, p0[0] + bias[0]),
                          __builtin_fmaf(wi0_[1], xv0, p0[1] + bias[1]),
                          __builtin_fmaf(wi0_[2], xv0, p0[2] + bias[2]),
                          __builtin_fmaf(wi0_[3], xv0, p0[3] + bias[3]), cA);
        float hB = gates_(__builtin_fmaf(wi0_[0], xv1, p1[0] + bias[0]),
                          __builtin_fmaf(wi0_[1], xv1, p1[1] + bias[1]),
                          __builtin_fmaf(wi0_[2], xv1, p1[2] + bias[2]),
                          __builtin_fmaf(wi0_[3], xv1, p1[3] + bias[3]), cB);
        hh[0][0][t & (NS - 1)][lane] = (_Float16)hA;
        hh[0][1][t & (NS - 1)][lane] = (_Float16)hB;
      }
      POSTP(0, k + 1);
    }
    __builtin_amdgcn_s_setprio(0);
  } else if (wave == 1) {  // a1 rec: reads pj[0][*]; -> hh[1][*]; consumer w5
    __builtin_amdgcn_s_setprio(1);
    for (int k = 0; k < NW; ++k) {
      WAITP(4, k + 1);
      if (k >= 4) { WAITP(5, k - 3); }
      const int t0 = k * CH;
      for (int s = 0; s < CH; ++s) {
        const int t = t0 + s;
        const int sl = (t + NS - 1) & (NS - 1);
        v8h A0, A1, B0, B1;
        ldafrag_(&hh[1][0][sl][0], q4, A0, A1);
        ldafrag_(&hh[1][1][sl][0], q4, B0, B1);
        float4 prA = *reinterpret_cast<const float4*>(&pj[0][0][t & (NS - 1)][lane * 4]);
        float4 prB = *reinterpret_cast<const float4*>(&pj[0][1][t & (NS - 1)][lane * 4]);
        float p0[4], p1[4];
        rec_pair_(u.bfr, A0, A1, B0, B1, s0, s1, p0, p1);
        float hA = gates_(p0[0] + bias[0] + prA.x, p0[1] + bias[1] + prA.y,
                          p0[2] + bias[2] + prA.z, p0[3] + bias[3] + prA.w, cA);
        float hB = gates_(p1[0] + bias[0] + prB.x, p1[1] + bias[1] + prB.y,
                          p1[2] + bias[2] + prB.z, p1[3] + bias[3] + prB.w, cB);
        hh[1][0][t & (NS - 1)][lane] = (_Float16)hA;
        hh[1][1][t & (NS - 1)][lane] = (_Float16)hB;
      }
      POSTP(1, k + 1);
    }
    __builtin_amdgcn_s_setprio(0);
  } else if (wave == 2) {  // a2 rec: reads pj[1][*]; -> hh[2][*]; consumer w3
    __builtin_amdgcn_s_setprio(1);
    for (int k = 0; k < NW; ++k) {
      WAITP(5, k + 1);
      if (k >= 4) { WAITP(3, k - 3); }
      const int t0 = k * CH;
      for (int s = 0; s < CH; ++s) {
        const int t = t0 + s;
        const int sl = (t + NS - 1) & (NS - 1);
        v8h A0, A1, B0, B1;
        ldafrag_(&hh[2][0][sl][0], q4, A0, A1);
        ldafrag_(&hh[2][1][sl][0], q4, B0, B1);
        float4 prA = *reinterpret_cast<const float4*>(&pj[1][0][t & (NS - 1)][lane * 4]);
        float4 prB = *reinterpret_cast<const float4*>(&pj[1][1][t & (NS - 1)][lane * 4]);
        float p0[4], p1[4];
        rec_pair_(u.bfr, A0, A1, B0, B1, s0, s1, p0, p1);
        float hA = gates_(p0[0] + bias[0] + prA.x, p0[1] + bias[1] + prA.y,
                          p0[2] + bias[2] + prA.z, p0[3] + bias[3] + prA.w, cA);
        float hB = gates_(p1[0] + bias[0] + prB.x, p1[1] + bias[1] + prB.y,
                          p1[2] + bias[2] + prB.z, p1[3] + bias[3] + prB.w, cB);
        hh[2][0][t & (NS - 1)][lane] = (_Float16)hA;
        hh[2][1][t & (NS - 1)][lane] = (_Float16)hB;
      }
      POSTP(2, k + 1);
    }
    __builtin_amdgcn_s_setprio(0);
  } else if (wave == 3) {  // b-chain: reads hh[2][*]
    for (int k = 0; k < NW; ++k) {
      WAITP(2, k + 1);
      const int t0 = k * CH;
      for (int s = 0; s < CH; ++s) {
        const int t = t0 + s;
        v2h hvA[32], hvB[32];
        load_h64(&hh[2][0][t & (NS - 1)][0], hvA);
        load_h64(&hh[2][1][t & (NS - 1)][0], hvB);
        float pgaA = bias[0], pgbA = 0.f, pgaB = bias[0], pgbB = 0.f;
#pragma unroll
        for (int j = 0; j < 16; ++j) {
          FDOT2(pgaA, u.wtb[0][j], hvA[j]);
          FDOT2(pgbA, u.wtb[1][j], hvA[16 + j]);
          FDOT2(pgaB, u.wtb[0][j], hvB[j]);
          FDOT2(pgbB, u.wtb[1][j], hvB[16 + j]);
        }
        float pgA = pgaA + pgbA, pgB = pgaB + pgbB;
        // element A chain
        {
          float p_i = qb_<0>(pgA), p_f = qb_<1>(pgA), p_g = qb_<2>(pgA), p_o = qb_<3>(pgA);
          float i0 = sig_(__builtin_fmaf(whb0[0], h0bA, p_i));
          float f0 = sig_(__builtin_fmaf(whb0[1], h0bA, p_f));
          float g0 = tanh_(__builtin_fmaf(whb0[2], h0bA, p_g));
          float o0 = sig_(__builtin_fmaf(whb0[3], h0bA, p_o));
          c0bA = __builtin_fmaf(f0, c0bA, i0 * g0);
          h0bA = o0 * tanh_(c0bA);
          float i1 = sig_(bb1[0] + __builtin_fmaf(wi1b[0], h0bA, wh1b[0] * h1bA));
          float f1 = sig_(bb1[1] + __builtin_fmaf(wi1b[1], h0bA, wh1b[1] * h1bA));
          float g1 = tanh_(bb1[2] + __builtin_fmaf(wi1b[2], h0bA, wh1b[2] * h1bA));
          float o1 = sig_(bb1[3] + __builtin_fmaf(wi1b[3], h0bA, wh1b[3] * h1bA));
          c1bA = __builtin_fmaf(f1, c1bA, i1 * g1);
          h1bA = o1 * tanh_(c1bA);
          float i2 = sig_(bb2[0] + __builtin_fmaf(wi2b[0], h1bA, wh2b[0] * h2bA));
          float f2 = sig_(bb2[1] + __builtin_fmaf(wi2b[1], h1bA, wh2b[1] * h2bA));
          float g2 = tanh_(bb2[2] + __builtin_fmaf(wi2b[2], h1bA, wh2b[2] * h2bA));
          float o2 = sig_(bb2[3] + __builtin_fmaf(wi2b[3], h1bA, wh2b[3] * h2bA));
          c2bA = __builtin_fmaf(f2, c2bA, i2 * g2);
          h2bA = o2 * tanh_(c2bA);
        }
        // element B chain (independent -> ILP with A's)
        {
          float p_i = qb_<0>(pgB), p_f = qb_<1>(pgB), p_g = qb_<2>(pgB), p_o = qb_<3>(pgB);
          float i0 = sig_(__builtin_fmaf(whb0[0], h0bB, p_i));
          float f0 = sig_(__builtin_fmaf(whb0[1], h0bB, p_f));
          float g0 = tanh_(__builtin_fmaf(whb0[2], h0bB, p_g));
          float o0 = sig_(__builtin_fmaf(whb0[3], h0bB, p_o));
          c0bB = __builtin_fmaf(f0, c0bB, i0 * g0);
          h0bB = o0 * tanh_(c0bB);
          float i1 = sig_(bb1[0] + __builtin_fmaf(wi1b[0], h0bB, wh1b[0] * h1bB));
          float f1 = sig_(bb1[1] + __builtin_fmaf(wi1b[1], h0bB, wh1b[1] * h1bB));
          float g1 = tanh_(bb1[2] + __builtin_fmaf(wi1b[2], h0bB, wh1b[2] * h1bB));
          float o1 = sig_(bb1[3] + __builtin_fmaf(wi1b[3], h0bB, wh1b[3] * h1bB));
          c1bB = __builtin_fmaf(f1, c1bB, i1 * g1);
          h1bB = o1 * tanh_(c1bB);
          float i2 = sig_(bb2[0] + __builtin_fmaf(wi2b[0], h1bB, wh2b[0] * h2bB));
          float f2 = sig_(bb2[1] + __builtin_fmaf(wi2b[1], h1bB, wh2b[1] * h2bB));
          float g2 = tanh_(bb2[2] + __builtin_fmaf(wi2b[2], h1bB, wh2b[2] * h2bB));
          float o2 = sig_(bb2[3] + __builtin_fmaf(wi2b[3], h1bB, wh2b[3] * h2bB));
          c2bB = __builtin_fmaf(f2, c2bB, i2 * g2);
          h2bB = o2 * tanh_(c2bB);
        }
        if (lane == 0) {
          out[(size_t)b0 * TT + t] = h2bA;
          out[(size_t)(b0 + 1) * TT + t] = h2bB;
        }
      }
      POSTP(3, k + 1);
    }
  } else if (wave == 4) {  // a1 proj MFMA: hh[0][e] -> pj[0][e]
    for (int k = 0; k < NW; ++k) {
      WAITP(0, k + 1);
      if (k >= 4) { WAITP(1, k - 3); }
      const int t0 = k * CH;
      const int slotb = (t0 + (lane & 15)) & (NS - 1);
      const bool wr = (lane & 15) < CH;
#pragma unroll
      for (int e = 0; e < 2; ++e) {
        v8h Bf0, Bf1;
        ldafrag_(&hh[0][e][slotb][0], q4, Bf0, Bf1);
        float* pbase = &pj[0][e][slotb][0] + 16 * q4;
#pragma unroll
        for (int tl = 0; tl < 16; ++tl) {
          v4f acc = __builtin_amdgcn_mfma_f32_16x16x32_f16(u.bfr[tl][0], Bf0, z, 0, 0, 0);
          acc = __builtin_amdgcn_mfma_f32_16x16x32_f16(u.bfr[tl][1], Bf1, acc, 0, 0, 0);
          if (wr) {
            const int o = 64 * (tl & 3) + (tl >> 2);
            pbase[o] = acc[0]; pbase[o + 4] = acc[1];
            pbase[o + 8] = acc[2]; pbase[o + 12] = acc[3];
          }
          __builtin_amdgcn_sched_barrier(0);
        }
      }
      POSTP(4, k + 1);
    }
  } else {                 // wave 5: a2 proj MFMA: hh[1][e] -> pj[1][e]
    for (int k = 0; k < NW; ++k) {
      WAITP(1, k + 1);
      if (k >= 4) { WAITP(2, k - 3); }
      const int t0 = k * CH;
      const int slotb = (t0 + (lane & 15)) & (NS - 1);
      const bool wr = (lane & 15) < CH;
#pragma unroll
      for (int e = 0; e < 2; ++e) {
        v8h Bf0, Bf1;
        ldafrag_(&hh[1][e][slotb][0], q4, Bf0, Bf1);
        float* pbase = &pj[1][e][slotb][0] + 16 * q4;
#pragma unroll
        for (int tl = 0; tl < 16; ++tl) {
          v4f acc = __builtin_amdgcn_mfma_f32_16x16x32_f16(u.bfr[tl][0], Bf0, z, 0, 0, 0);
          acc = __builtin_amdgcn_mfma_f32_16x16x32_f16(u.bfr[tl][1], Bf1, acc, 0, 0, 0);
          if (wr) {
            const int o = 64 * (tl & 3) + (tl >> 2);
            pbase[o] = acc[0]; pbase[o + 4] = acc[1];
            pbase[o + 8] = acc[2]; pbase[o + 12] = acc[3];
          }
          __builtin_amdgcn_sched_barrier(0);
        }
      }
      POSTP(5, k + 1);
    }
  }
}

extern "C" void kernel_launch(void* const* d_in, const int* in_sizes, int n_in,
                              void* d_out, int out_size, void* d_ws, size_t ws_size,
                              hipStream_t stream) {
  const float* x      = (const float*)d_in[0];
  const float* wih_a0 = (const float*)d_in[1];
  const float* whh_a0 = (const float*)d_in[2];
  const float* bih_a0 = (const float*)d_in[3];
  const float* bhh_a0 = (const float*)d_in[4];
  const float* wih_a1 = (const float*)d_in[5];
  const float* whh_a1 = (const float*)d_in[6];
  const float* bih_a1 = (const float*)d_in[7];
  const float* bhh_a1 = (const float*)d_in[8];
  const float* wih_a2 = (const float*)d_in[9];
  const float* whh_a2 = (const float*)d_in[10];
  const float* bih_a2 = (const float*)d_in[11];
  const float* bhh_a2 = (const float*)d_in[12];
  const float* wih_b0 = (const float*)d_in[13];
  const float* whh_b0 = (const float*)d_in[14];
  const float* bih_b0 = (const float*)d_in[15];
  const float* bhh_b0 = (const float*)d_in[16];
  const float* wih_b1 = (const float*)d_in[17];
  const float* whh_b1 = (const float*)d_in[18];
  const float* bih_b1 = (const float*)d_in[19];
  const float* bhh_b1 = (const float*)d_in[20];
  const float* wih_b2 = (const float*)d_in[21];
  const float* whh_b2 = (const float*)d_in[22];
  const float* bih_b2 = (const float*)d_in[23];
  const float* bhh_b2 = (const float*)d_in[24];
  float* out = (float*)d_out;

  lstm_pipe_k<<<NB, 384, 0, stream>>>(
      x,
      wih_a0, whh_a0, bih_a0, bhh_a0,
      wih_a1, whh_a1, bih_a1, bhh_a1,
      wih_a2, whh_a2, bih_a2, bhh_a2,
      wih_b0, whh_b0, bih_b0, bhh_b0,
      wih_b1, whh_b1, bih_b1, bhh_b1,
      wih_b2, whh_b2, bih_b2, bhh_b2,
      out);
}

// Round 14
// 347.892 us; speedup vs baseline: 1.5780x; 1.5780x over previous
//
#include <hip/hip_runtime.h>

// AttackLSTM R29 — R27 base + register-direct A-fragments via ds_bpermute.
// R28 post-mortem: 128-block geometry idles half the CUs; dual-chain
// interleave gained only ~10% per step -> net 474us. REVERTED to R27.
// R29 theory: R27's rec self-loop (1240cy/step vs ~500 static) carries a
// full LDS write->read RT per step ONLY to redistribute h across lanes
// (lane=hid -> A-frag layout). Replace with register cross-lane: 1 DPP
// quad-perm (h[m^1]) + 2 cndmask + RNE f16 pack -> pair words; then 8x
// ds_bpermute_b32 (precomputed addrs: pair p=8c+2q4+w at src lane 2p)
// rebuild A0/A1 exactly per the validated ldafrag_ mapping. The hh write
// (for proj/b consumers) is DEFERRED one step so it queues BEHIND the
// bpermutes (in-order DS pipe never blocks them); window-end flush before
// POSTP keeps the sync protocol identical. Everything else verbatim R27:
// 256 blocks, CH=4/NS=16, MFMA proj (wr<CH), b-chain, prog[6] self-timed.
// Verify: absmax=0 (bit-identical numerics), WRITE ~512KB, dur 205-240us.

#define BB 256
#define TT 512
#define CH 4
#define NS 16  // ring slots -> 4-window slack
#define NW (TT / CH)
#define HP 72   // padded hh row (halfs): 144B
#define PP 260  // padded pj row (floats): 1040B

typedef _Float16 v2h __attribute__((ext_vector_type(2)));
typedef _Float16 v8h __attribute__((ext_vector_type(8)));
typedef float v4f __attribute__((ext_vector_type(4)));

__device__ __forceinline__ float sig_(float x) {
  return __builtin_amdgcn_rcpf(1.f + __builtin_amdgcn_exp2f(-1.44269504f * x));
}
__device__ __forceinline__ float tanh_(float x) {
  return __builtin_fmaf(2.f, __builtin_amdgcn_rcpf(1.f + __builtin_amdgcn_exp2f(-2.88539008f * x)), -1.f);
}

template <int K>
__device__ __forceinline__ float qb_(float v) {
  return __int_as_float(__builtin_amdgcn_update_dpp(
      0, __float_as_int(v), (K | (K << 2) | (K << 4) | (K << 6)), 0xF, 0xF, true));
}

#if __has_builtin(__builtin_amdgcn_fdot2)
#define FDOT2(acc, a, b) (acc) = __builtin_amdgcn_fdot2((a), (b), (acc), false)
#else
#define FDOT2(acc, a, b) \
  (acc) = __builtin_fmaf((float)(a)[0], (float)(b)[0], \
          __builtin_fmaf((float)(a)[1], (float)(b)[1], (acc)))
#endif
#define KEEPP(a) asm volatile("" : "+v"(a))
#define PIN16(w)                                                            \
  do {                                                                      \
    _Pragma("unroll") for (int _i = 0; _i < 16; ++_i) KEEPP((w)[_i]);       \
  } while (0)

// Spin until prog[i] >= v (acquire), sleeping between polls.
#define WAITP(i, v)                                                           \
  while (__hip_atomic_load(&prog[i], __ATOMIC_ACQUIRE,                        \
                           __HIP_MEMORY_SCOPE_WORKGROUP) < (v)) {             \
    __builtin_amdgcn_s_sleep(1);                                              \
  }
// Publish prog[i] = v after all this wave's data ds_writes retired.
#define POSTP(i, v)                                                           \
  do {                                                                        \
    asm volatile("s_waitcnt lgkmcnt(0)" ::: "memory");                        \
    if (lane == 0)                                                            \
      __hip_atomic_store(&prog[i], (v), __ATOMIC_RELEASE,                     \
                         __HIP_MEMORY_SCOPE_WORKGROUP);                       \
  } while (0)

__device__ __forceinline__ v2h bc2h_(int v) { return __builtin_bit_cast(v2h, v); }

// 64 halfs from LDS as 32 v2h via int4 reads (8x ds_read_b128, broadcast).
__device__ __forceinline__ void load_h64(const _Float16* p, v2h hv[32]) {
  const int4* hp = reinterpret_cast<const int4*>(p);
#pragma unroll
  for (int i = 0; i < 8; ++i) {
    int4 blk = hp[i];
    hv[4 * i + 0] = bc2h_(blk.x);
    hv[4 * i + 1] = bc2h_(blk.y);
    hv[4 * i + 2] = bc2h_(blk.z);
    hv[4 * i + 3] = bc2h_(blk.w);
  }
}

// fp32 row of 64 -> two 16-v2h halves (b-chain).
__device__ __forceinline__ void load_row_pair(const float* src, v2h* lo, v2h* hi) {
  const float4* p = reinterpret_cast<const float4*>(src);
#pragma unroll
  for (int i = 0; i < 8; ++i) {
    float4 v = p[i];
    lo[2 * i]     = v2h{(_Float16)v.x, (_Float16)v.y};
    lo[2 * i + 1] = v2h{(_Float16)v.z, (_Float16)v.w};
  }
#pragma unroll
  for (int i = 0; i < 8; ++i) {
    float4 v = p[8 + i];
    hi[2 * i]     = v2h{(_Float16)v.x, (_Float16)v.y};
    hi[2 * i + 1] = v2h{(_Float16)v.z, (_Float16)v.w};
  }
}

// W-fragment for tile t, K-chunk kc of W[256x64] row-major f32 (validated).
__device__ __forceinline__ v8h ldbfrag_(const float* W, int t, int kc, int lane) {
  const int row = 16 * t + (lane & 15);
  const float* p = W + row * 64 + 32 * kc + 4 * (lane >> 4);
  float4 fa = *reinterpret_cast<const float4*>(p);
  float4 fb = *reinterpret_cast<const float4*>(p + 16);
  return v8h{(_Float16)fa.x, (_Float16)fa.y, (_Float16)fa.z, (_Float16)fa.w,
             (_Float16)fb.x, (_Float16)fb.y, (_Float16)fb.z, (_Float16)fb.w};
}

// A-fragment pair from an hh slot (proj waves; validated layout).
__device__ __forceinline__ void ldafrag_(const _Float16* hprev, int q4,
                                         v8h& A0, v8h& A1) {
  const char* hp = (const char*)hprev + 8 * q4;
  int2 r00 = *(const int2*)(hp);
  int2 r01 = *(const int2*)(hp + 32);
  int2 r10 = *(const int2*)(hp + 64);
  int2 r11 = *(const int2*)(hp + 96);
  A0 = __builtin_bit_cast(v8h, int4{r00.x, r00.y, r01.x, r01.y});
  A1 = __builtin_bit_cast(v8h, int4{r10.x, r10.y, r11.x, r11.y});
}

// Register-direct A-fragments from per-lane h (lane=hid), no LDS round-trip.
// Pack pair (h[2m],h[2m+1]) in every lane via DPP quad_perm [1,0,3,2], then
// 8 bpermutes gather pair words: A0 words = pairs {2q4,2q4+1,8+2q4,8+2q4+1},
// A1 = +16,+24 (matches ldafrag_ exactly; RNE f16 = bit-identical to store).
__device__ __forceinline__ void regafrag_(float hA, int lane, const int ba[8],
                                          v8h& A0, v8h& A1) {
  int hnb = __builtin_amdgcn_update_dpp(0, __float_as_int(hA), 0xB1, 0xF, 0xF, true);
  float hn = __int_as_float(hnb);
  float lo = (lane & 1) ? hn : hA;
  float hi = (lane & 1) ? hA : hn;
  int pkw = __builtin_bit_cast(int, v2h{(_Float16)lo, (_Float16)hi});
  int w0 = __builtin_amdgcn_ds_bpermute(ba[0], pkw);
  int w1 = __builtin_amdgcn_ds_bpermute(ba[1], pkw);
  int w2 = __builtin_amdgcn_ds_bpermute(ba[2], pkw);
  int w3 = __builtin_amdgcn_ds_bpermute(ba[3], pkw);
  int w4 = __builtin_amdgcn_ds_bpermute(ba[4], pkw);
  int w5 = __builtin_amdgcn_ds_bpermute(ba[5], pkw);
  int w6 = __builtin_amdgcn_ds_bpermute(ba[6], pkw);
  int w7 = __builtin_amdgcn_ds_bpermute(ba[7], pkw);
  A0 = __builtin_bit_cast(v8h, int4{w0, w1, w2, w3});
  A1 = __builtin_bit_cast(v8h, int4{w4, w5, w6, w7});
}

// Single-element rec matvec (R22/R27-validated): 32 MFMAs, extract 4 gates.
__device__ __forceinline__ void rec_mv_(const v8h bfr[16][2],
                                        const v8h& A0, const v8h& A1,
                                        bool s0, bool s1, float p[4]) {
  const v4f z = {0.f, 0.f, 0.f, 0.f};
  v4f acc[16];
#pragma unroll
  for (int tl = 0; tl < 16; ++tl) {
    v4f d = __builtin_amdgcn_mfma_f32_16x16x32_f16(A0, bfr[tl][0], z, 0, 0, 0);
    acc[tl] = __builtin_amdgcn_mfma_f32_16x16x32_f16(A1, bfr[tl][1], d, 0, 0, 0);
  }
#pragma unroll
  for (int g = 0; g < 4; ++g) {
    float v01 = s0 ? acc[4 * g + 1][0] : acc[4 * g + 0][0];
    float v23 = s0 ? acc[4 * g + 3][0] : acc[4 * g + 2][0];
    p[g] = s1 ? v23 : v01;
  }
}

__global__ __attribute__((amdgpu_flat_work_group_size(384, 384),
                          amdgpu_waves_per_eu(2, 2)))
void lstm_pipe_k(
    const float* __restrict__ x,
    const float* __restrict__ wih_a0, const float* __restrict__ whh_a0,
    const float* __restrict__ bih_a0, const float* __restrict__ bhh_a0,
    const float* __restrict__ wih_a1, const float* __restrict__ whh_a1,
    const float* __restrict__ bih_a1, const float* __restrict__ bhh_a1,
    const float* __restrict__ wih_a2, const float* __restrict__ whh_a2,
    const float* __restrict__ bih_a2, const float* __restrict__ bhh_a2,
    const float* __restrict__ wih_b0, const float* __restrict__ whh_b0,
    const float* __restrict__ bih_b0, const float* __restrict__ bhh_b0,
    const float* __restrict__ wih_b1, const float* __restrict__ whh_b1,
    const float* __restrict__ bih_b1, const float* __restrict__ bhh_b1,
    const float* __restrict__ wih_b2, const float* __restrict__ whh_b2,
    const float* __restrict__ bih_b2, const float* __restrict__ bhh_b2,
    float* __restrict__ out)  // [B,T]
{
  const int b = blockIdx.x;
  const int tid = threadIdx.x;
  const int wave = tid >> 6;
  const int lane = tid & 63;

  __shared__ __align__(16) _Float16 hh[3][NS][HP];  // h rings (padded rows)
  __shared__ __align__(16) float pj[2][NS][PP];     // proj rings (padded rows)
  __shared__ float xs[TT];
  __shared__ int prog[6];                           // per-wave windows done

  for (int i = tid; i < TT; i += 384) xs[i] = x[(size_t)b * TT + i];
  for (int i = tid; i < 3 * NS * HP / 2; i += 384) reinterpret_cast<int*>(hh)[i] = 0;
  if (tid < 6) prog[tid] = 0;

  union UW {
    v8h bfr[16][2];
    v2h wtb[2][16];
  } u;

  float bias[4] = {0.f, 0.f, 0.f, 0.f};
  float wi0_[4] = {0.f, 0.f, 0.f, 0.f};
  float whb0[4] = {}, wi1b[4] = {}, wh1b[4] = {}, bb1[4] = {},
        wi2b[4] = {}, wh2b[4] = {}, bb2[4] = {};

  if (wave == 0) {  // a0 rec: B = whh_a0 fragments
#pragma unroll
    for (int t = 0; t < 16; ++t) {
      u.bfr[t][0] = ldbfrag_(whh_a0, t, 0, lane);
      u.bfr[t][1] = ldbfrag_(whh_a0, t, 1, lane);
    }
#pragma unroll
    for (int q = 0; q < 4; ++q) {
      const int row = q * 64 + lane;
      bias[q] = bih_a0[row] + bhh_a0[row];
      wi0_[q] = wih_a0[row];
    }
  } else if (wave == 1) {  // a1 rec
#pragma unroll
    for (int t = 0; t < 16; ++t) {
      u.bfr[t][0] = ldbfrag_(whh_a1, t, 0, lane);
      u.bfr[t][1] = ldbfrag_(whh_a1, t, 1, lane);
    }
#pragma unroll
    for (int q = 0; q < 4; ++q) bias[q] = bih_a1[q * 64 + lane] + bhh_a1[q * 64 + lane];
  } else if (wave == 2) {  // a2 rec
#pragma unroll
    for (int t = 0; t < 16; ++t) {
      u.bfr[t][0] = ldbfrag_(whh_a2, t, 0, lane);
      u.bfr[t][1] = ldbfrag_(whh_a2, t, 1, lane);
    }
#pragma unroll
    for (int q = 0; q < 4; ++q) bias[q] = bih_a2[q * 64 + lane] + bhh_a2[q * 64 + lane];
  } else if (wave == 3) {  // b-chain
    const int q = lane & 3;
    load_row_pair(wih_b0 + q * 64, u.wtb[0], u.wtb[1]);
    bias[0] = bih_b0[q] + bhh_b0[q];
#pragma unroll
    for (int k = 0; k < 4; ++k) {
      whb0[k] = whh_b0[k];
      wi1b[k] = wih_b1[k]; wh1b[k] = whh_b1[k]; bb1[k] = bih_b1[k] + bhh_b1[k];
      wi2b[k] = wih_b2[k]; wh2b[k] = whh_b2[k]; bb2[k] = bih_b2[k] + bhh_b2[k];
    }
    PIN16(u.wtb[0]); PIN16(u.wtb[1]);
  } else if (wave == 4) {  // a1 proj MFMA: W = wih_a1
#pragma unroll
    for (int t = 0; t < 16; ++t) {
      u.bfr[t][0] = ldbfrag_(wih_a1, t, 0, lane);
      u.bfr[t][1] = ldbfrag_(wih_a1, t, 1, lane);
    }
  } else {                 // wave 5: a2 proj MFMA: W = wih_a2
#pragma unroll
    for (int t = 0; t < 16; ++t) {
      u.bfr[t][0] = ldbfrag_(wih_a2, t, 0, lane);
      u.bfr[t][1] = ldbfrag_(wih_a2, t, 1, lane);
    }
  }
  __syncthreads();

  float c = 0.f;
  float h0b = 0.f, c0b = 0.f, h1b = 0.f, c1b = 0.f, h2b = 0.f, c2b = 0.f;
  const int q4 = lane >> 4;
  const bool s0 = q4 & 1, s1 = q4 & 2;
  const v4f z = {0.f, 0.f, 0.f, 0.f};

  // bpermute addresses for regafrag_ (constant per lane).
  int ba[8];
#pragma unroll
  for (int cc = 0; cc < 4; ++cc) {
#pragma unroll
    for (int w = 0; w < 2; ++w) ba[cc * 2 + w] = 4 * (16 * cc + 4 * q4 + 2 * w);
  }

  if (wave == 0) {  // a0 rec -> hh[0]; consumer w4
    __builtin_amdgcn_s_setprio(1);
    float hA = 0.f;  // h(t-1) register (lane = hid)
    for (int k = 0; k < NW; ++k) {
      if (k >= 4) { WAITP(4, k - 3); }
      const int t0 = k * CH;
      for (int s = 0; s < CH; ++s) {
        const int t = t0 + s;
        v8h A0, A1;
        regafrag_(hA, lane, ba, A0, A1);           // cross-lane, no LDS RT
        if (s > 0) hh[0][(t - 1) & (NS - 1)][lane] = (_Float16)hA;  // deferred
        float p[4];
        rec_mv_(u.bfr, A0, A1, s0, s1, p);
        const float xv = xs[t];
        float p0 = __builtin_fmaf(wi0_[0], xv, p[0] + bias[0]);
        float p1 = __builtin_fmaf(wi0_[1], xv, p[1] + bias[1]);
        float p2 = __builtin_fmaf(wi0_[2], xv, p[2] + bias[2]);
        float p3 = __builtin_fmaf(wi0_[3], xv, p[3] + bias[3]);
        float gi = sig_(p0), gf = sig_(p1), gg = tanh_(p2), go = sig_(p3);
        c = __builtin_fmaf(gf, c, gi * gg);
        hA = go * tanh_(c);
      }
      hh[0][(t0 + CH - 1) & (NS - 1)][lane] = (_Float16)hA;  // window flush
      POSTP(0, k + 1);
    }
    __builtin_amdgcn_s_setprio(0);
  } else if (wave == 1) {  // a1 rec: reads pj[0]; -> hh[1]; consumer w5
    __builtin_amdgcn_s_setprio(1);
    float hA = 0.f;
    for (int k = 0; k < NW; ++k) {
      WAITP(4, k + 1);
      if (k >= 4) { WAITP(5, k - 3); }
      const int t0 = k * CH;
      for (int s = 0; s < CH; ++s) {
        const int t = t0 + s;
        v8h A0, A1;
        regafrag_(hA, lane, ba, A0, A1);
        if (s > 0) hh[1][(t - 1) & (NS - 1)][lane] = (_Float16)hA;
        float4 pr = *reinterpret_cast<const float4*>(&pj[0][t & (NS - 1)][lane * 4]);
        float p[4];
        rec_mv_(u.bfr, A0, A1, s0, s1, p);
        float p0 = p[0] + bias[0] + pr.x;
        float p1 = p[1] + bias[1] + pr.y;
        float p2 = p[2] + bias[2] + pr.z;
        float p3 = p[3] + bias[3] + pr.w;
        float gi = sig_(p0), gf = sig_(p1), gg = tanh_(p2), go = sig_(p3);
        c = __builtin_fmaf(gf, c, gi * gg);
        hA = go * tanh_(c);
      }
      hh[1][(t0 + CH - 1) & (NS - 1)][lane] = (_Float16)hA;
      POSTP(1, k + 1);
    }
    __builtin_amdgcn_s_setprio(0);
  } else if (wave == 2) {  // a2 rec: reads pj[1]; -> hh[2]; consumer w3
    __builtin_amdgcn_s_setprio(1);
    float hA = 0.f;
    for (int k = 0; k < NW; ++k) {
      WAITP(5, k + 1);
      if (k >= 4) { WAITP(3, k - 3); }
      const int t0 = k * CH;
      for (int s = 0; s < CH; ++s) {
        const int t = t0 + s;
        v8h A0, A1;
        regafrag_(hA, lane, ba, A0, A1);
        if (s > 0) hh[2][(t - 1) & (NS - 1)][lane] = (_Float16)hA;
        float4 pr = *reinterpret_cast<const float4*>(&pj[1][t & (NS - 1)][lane * 4]);
        float p[4];
        rec_mv_(u.bfr, A0, A1, s0, s1, p);
        float p0 = p[0] + bias[0] + pr.x;
        float p1 = p[1] + bias[1] + pr.y;
        float p2 = p[2] + bias[2] + pr.z;
        float p3 = p[3] + bias[3] + pr.w;
        float gi = sig_(p0), gf = sig_(p1), gg = tanh_(p2), go = sig_(p3);
        c = __builtin_fmaf(gf, c, gi * gg);
        hA = go * tanh_(c);
      }
      hh[2][(t0 + CH - 1) & (NS - 1)][lane] = (_Float16)hA;
      POSTP(2, k + 1);
    }
    __builtin_amdgcn_s_setprio(0);
  } else if (wave == 3) {  // b-chain: reads hh[2]
    for (int k = 0; k < NW; ++k) {
      WAITP(2, k + 1);
      const int t0 = k * CH;
      for (int s = 0; s < CH; ++s) {
        const int t = t0 + s;
        v2h hv[32];
        load_h64(&hh[2][t & (NS - 1)][0], hv);
        float pga = bias[0], pgb = 0.f;
#pragma unroll
        for (int j = 0; j < 16; ++j) {
          FDOT2(pga, u.wtb[0][j], hv[j]);
          FDOT2(pgb, u.wtb[1][j], hv[16 + j]);
        }
        float pg = pga + pgb;
        float p_i = qb_<0>(pg), p_f = qb_<1>(pg), p_g = qb_<2>(pg), p_o = qb_<3>(pg);
        float i0 = sig_(__builtin_fmaf(whb0[0], h0b, p_i));
        float f0 = sig_(__builtin_fmaf(whb0[1], h0b, p_f));
        float g0 = tanh_(__builtin_fmaf(whb0[2], h0b, p_g));
        float o0 = sig_(__builtin_fmaf(whb0[3], h0b, p_o));
        c0b = __builtin_fmaf(f0, c0b, i0 * g0);
        h0b = o0 * tanh_(c0b);
        float i1 = sig_(bb1[0] + __builtin_fmaf(wi1b[0], h0b, wh1b[0] * h1b));
        float f1 = sig_(bb1[1] + __builtin_fmaf(wi1b[1], h0b, wh1b[1] * h1b));
        float g1 = tanh_(bb1[2] + __builtin_fmaf(wi1b[2], h0b, wh1b[2] * h1b));
        float o1 = sig_(bb1[3] + __builtin_fmaf(wi1b[3], h0b, wh1b[3] * h1b));
        c1b = __builtin_fmaf(f1, c1b, i1 * g1);
        h1b = o1 * tanh_(c1b);
        float i2 = sig_(bb2[0] + __builtin_fmaf(wi2b[0], h1b, wh2b[0] * h2b));
        float f2 = sig_(bb2[1] + __builtin_fmaf(wi2b[1], h1b, wh2b[1] * h2b));
        float g2 = tanh_(bb2[2] + __builtin_fmaf(wi2b[2], h1b, wh2b[2] * h2b));
        float o2 = sig_(bb2[3] + __builtin_fmaf(wi2b[3], h1b, wh2b[3] * h2b));
        c2b = __builtin_fmaf(f2, c2b, i2 * g2);
        h2b = o2 * tanh_(c2b);
        if (lane == 0) out[(size_t)b * TT + t] = h2b;
      }
      POSTP(3, k + 1);
    }
  } else if (wave == 4) {  // a1 proj MFMA: hh[0] window k -> pj[0] window k
    for (int k = 0; k < NW; ++k) {
      WAITP(0, k + 1);
      if (k >= 4) { WAITP(1, k - 3); }
      const int t0 = k * CH;
      const int slotb = (t0 + (lane & 15)) & (NS - 1);
      v8h Bf0, Bf1;
      ldafrag_(&hh[0][slotb][0], q4, Bf0, Bf1);
      float* pbase = &pj[0][slotb][0] + 16 * q4;
      const bool wr = (lane & 15) < CH;  // cols >= CH garbage (other windows)
#pragma unroll
      for (int tl = 0; tl < 16; ++tl) {
        v4f acc = __builtin_amdgcn_mfma_f32_16x16x32_f16(u.bfr[tl][0], Bf0, z, 0, 0, 0);
        acc = __builtin_amdgcn_mfma_f32_16x16x32_f16(u.bfr[tl][1], Bf1, acc, 0, 0, 0);
        if (wr) {
          const int o = 64 * (tl & 3) + (tl >> 2);
          pbase[o] = acc[0]; pbase[o + 4] = acc[1];
          pbase[o + 8] = acc[2]; pbase[o + 12] = acc[3];
        }
        __builtin_amdgcn_sched_barrier(0);
      }
      POSTP(4, k + 1);
    }
  } else {                 // wave 5: a2 proj MFMA: hh[1] window k -> pj[1]
    for (int k = 0; k < NW; ++k) {
      WAITP(1, k + 1);
      if (k >= 4) { WAITP(2, k - 3); }
      const int t0 = k * CH;
      const int slotb = (t0 + (lane & 15)) & (NS - 1);
      v8h Bf0, Bf1;
      ldafrag_(&hh[1][slotb][0], q4, Bf0, Bf1);
      float* pbase = &pj[1][slotb][0] + 16 * q4;
      const bool wr = (lane & 15) < CH;
#pragma unroll
      for (int tl = 0; tl < 16; ++tl) {
        v4f acc = __builtin_amdgcn_mfma_f32_16x16x32_f16(u.bfr[tl][0], Bf0, z, 0, 0, 0);
        acc = __builtin_amdgcn_mfma_f32_16x16x32_f16(u.bfr[tl][1], Bf1, acc, 0, 0, 0);
        if (wr) {
          const int o = 64 * (tl & 3) + (tl >> 2);
          pbase[o] = acc[0]; pbase[o + 4] = acc[1];
          pbase[o + 8] = acc[2]; pbase[o + 12] = acc[3];
        }
        __builtin_amdgcn_sched_barrier(0);
      }
      POSTP(5, k + 1);
    }
  }
}

extern "C" void kernel_launch(void* const* d_in, const int* in_sizes, int n_in,
                              void* d_out, int out_size, void* d_ws, size_t ws_size,
                              hipStream_t stream) {
  const float* x      = (const float*)d_in[0];
  const float* wih_a0 = (const float*)d_in[1];
  const float* whh_a0 = (const float*)d_in[2];
  const float* bih_a0 = (const float*)d_in[3];
  const float* bhh_a0 = (const float*)d_in[4];
  const float* wih_a1 = (const float*)d_in[5];
  const float* whh_a1 = (const float*)d_in[6];
  const float* bih_a1 = (const float*)d_in[7];
  const float* bhh_a1 = (const float*)d_in[8];
  const float* wih_a2 = (const float*)d_in[9];
  const float* whh_a2 = (const float*)d_in[10];
  const float* bih_a2 = (const float*)d_in[11];
  const float* bhh_a2 = (const float*)d_in[12];
  const float* wih_b0 = (const float*)d_in[13];
  const float* whh_b0 = (const float*)d_in[14];
  const float* bih_b0 = (const float*)d_in[15];
  const float* bhh_b0 = (const float*)d_in[16];
  const float* wih_b1 = (const float*)d_in[17];
  const float* whh_b1 = (const float*)d_in[18];
  const float* bih_b1 = (const float*)d_in[19];
  const float* bhh_b1 = (const float*)d_in[20];
  const float* wih_b2 = (const float*)d_in[21];
  const float* whh_b2 = (const float*)d_in[22];
  const float* bih_b2 = (const float*)d_in[23];
  const float* bhh_b2 = (const float*)d_in[24];
  float* out = (float*)d_out;

  lstm_pipe_k<<<BB, 384, 0, stream>>>(
      x,
      wih_a0, whh_a0, bih_a0, bhh_a0,
      wih_a1, whh_a1, bih_a1, bhh_a1,
      wih_a2, whh_a2, bih_a2, bhh_a2,
      wih_b0, whh_b0, bih_b0, bhh_b0,
      wih_b1, whh_b1, bih_b1, bhh_b1,
      wih_b2, whh_b2, bih_b2, bhh_b2,
      out);
}

// Round 15
// 336.777 us; speedup vs baseline: 1.6300x; 1.0330x over previous
//
#include <hip/hip_runtime.h>

// AttackLSTM R30 — R27 base + matrix-pipe rebalance (8 waves) + pj prefetch.
// R29 post-mortem: bpermute A-frags 279us vs R27 265 -> self-loop LDS RT not
// binding; reverted. Model closure: lone-wave MFMA cadence ~12-15cy (m06's
// 4.85cy needs high occupancy to hide per-wave issue gaps) -> rec = ~480cy
// MFMA + proj wave sharing the SAME SIMD matrix pipe (+120cy) + reads +
// gates = ~1240cy = measured. Binding resource = S0/S1 matrix pipes shared
// rec+proj. R30: 512 thr / 8 waves; w0-w2 rec on S0-S2, w3 b on S3,
// w4/w5 exit after init barrier (no later barriers -> safe), w6(S2)=a2proj,
// w7(S3)=a1proj. Pipe loads 40/40/32/0 -> 32/32/40/8. Plus pj prefetch one
// step ahead in a1/a2 rec. Everything else verbatim R27 (CH=4/NS=16,
// MFMA rec+proj, padded rings, prog[] self-timed).
// Chain: w0 -> w7(a1proj) -> w1 -> w6(a2proj) -> w2 -> w3.
// Verify: dur ~235-255us steady, WRITE ~512KB, absmax=0.

#define BB 256
#define TT 512
#define CH 4
#define NS 16  // ring slots -> 4-window slack
#define NW (TT / CH)
#define HP 72   // padded hh row (halfs): 144B
#define PP 260  // padded pj row (floats): 1040B

typedef _Float16 v2h __attribute__((ext_vector_type(2)));
typedef _Float16 v8h __attribute__((ext_vector_type(8)));
typedef float v4f __attribute__((ext_vector_type(4)));

__device__ __forceinline__ float sig_(float x) {
  return __builtin_amdgcn_rcpf(1.f + __builtin_amdgcn_exp2f(-1.44269504f * x));
}
__device__ __forceinline__ float tanh_(float x) {
  return __builtin_fmaf(2.f, __builtin_amdgcn_rcpf(1.f + __builtin_amdgcn_exp2f(-2.88539008f * x)), -1.f);
}

template <int K>
__device__ __forceinline__ float qb_(float v) {
  return __int_as_float(__builtin_amdgcn_update_dpp(
      0, __float_as_int(v), (K | (K << 2) | (K << 4) | (K << 6)), 0xF, 0xF, true));
}

#if __has_builtin(__builtin_amdgcn_fdot2)
#define FDOT2(acc, a, b) (acc) = __builtin_amdgcn_fdot2((a), (b), (acc), false)
#else
#define FDOT2(acc, a, b) \
  (acc) = __builtin_fmaf((float)(a)[0], (float)(b)[0], \
          __builtin_fmaf((float)(a)[1], (float)(b)[1], (acc)))
#endif
#define KEEPP(a) asm volatile("" : "+v"(a))
#define PIN16(w)                                                            \
  do {                                                                      \
    _Pragma("unroll") for (int _i = 0; _i < 16; ++_i) KEEPP((w)[_i]);       \
  } while (0)

// Spin until prog[i] >= v (acquire), sleeping between polls.
#define WAITP(i, v)                                                           \
  while (__hip_atomic_load(&prog[i], __ATOMIC_ACQUIRE,                        \
                           __HIP_MEMORY_SCOPE_WORKGROUP) < (v)) {             \
    __builtin_amdgcn_s_sleep(1);                                              \
  }
// Publish prog[i] = v after all this wave's data ds_writes retired.
#define POSTP(i, v)                                                           \
  do {                                                                        \
    asm volatile("s_waitcnt lgkmcnt(0)" ::: "memory");                        \
    if (lane == 0)                                                            \
      __hip_atomic_store(&prog[i], (v), __ATOMIC_RELEASE,                     \
                         __HIP_MEMORY_SCOPE_WORKGROUP);                       \
  } while (0)

__device__ __forceinline__ v2h bc2h_(int v) { return __builtin_bit_cast(v2h, v); }

// 64 halfs from LDS as 32 v2h via int4 reads (8x ds_read_b128, broadcast).
__device__ __forceinline__ void load_h64(const _Float16* p, v2h hv[32]) {
  const int4* hp = reinterpret_cast<const int4*>(p);
#pragma unroll
  for (int i = 0; i < 8; ++i) {
    int4 blk = hp[i];
    hv[4 * i + 0] = bc2h_(blk.x);
    hv[4 * i + 1] = bc2h_(blk.y);
    hv[4 * i + 2] = bc2h_(blk.z);
    hv[4 * i + 3] = bc2h_(blk.w);
  }
}

// fp32 row of 64 -> two 16-v2h halves (b-chain).
__device__ __forceinline__ void load_row_pair(const float* src, v2h* lo, v2h* hi) {
  const float4* p = reinterpret_cast<const float4*>(src);
#pragma unroll
  for (int i = 0; i < 8; ++i) {
    float4 v = p[i];
    lo[2 * i]     = v2h{(_Float16)v.x, (_Float16)v.y};
    lo[2 * i + 1] = v2h{(_Float16)v.z, (_Float16)v.w};
  }
#pragma unroll
  for (int i = 0; i < 8; ++i) {
    float4 v = p[8 + i];
    hi[2 * i]     = v2h{(_Float16)v.x, (_Float16)v.y};
    hi[2 * i + 1] = v2h{(_Float16)v.z, (_Float16)v.w};
  }
}

// W-fragment for tile t, K-chunk kc of W[256x64] row-major f32 (validated).
__device__ __forceinline__ v8h ldbfrag_(const float* W, int t, int kc, int lane) {
  const int row = 16 * t + (lane & 15);
  const float* p = W + row * 64 + 32 * kc + 4 * (lane >> 4);
  float4 fa = *reinterpret_cast<const float4*>(p);
  float4 fb = *reinterpret_cast<const float4*>(p + 16);
  return v8h{(_Float16)fa.x, (_Float16)fa.y, (_Float16)fa.z, (_Float16)fa.w,
             (_Float16)fb.x, (_Float16)fb.y, (_Float16)fb.z, (_Float16)fb.w};
}

// A-fragment pair from an hh slot (validated layout).
__device__ __forceinline__ void ldafrag_(const _Float16* hprev, int q4,
                                         v8h& A0, v8h& A1) {
  const char* hp = (const char*)hprev + 8 * q4;
  int2 r00 = *(const int2*)(hp);
  int2 r01 = *(const int2*)(hp + 32);
  int2 r10 = *(const int2*)(hp + 64);
  int2 r11 = *(const int2*)(hp + 96);
  A0 = __builtin_bit_cast(v8h, int4{r00.x, r00.y, r01.x, r01.y});
  A1 = __builtin_bit_cast(v8h, int4{r10.x, r10.y, r11.x, r11.y});
}

// Single-element rec matvec (R22/R27-validated): 32 MFMAs, extract 4 gates.
__device__ __forceinline__ void rec_mv_(const v8h bfr[16][2],
                                        const v8h& A0, const v8h& A1,
                                        bool s0, bool s1, float p[4]) {
  const v4f z = {0.f, 0.f, 0.f, 0.f};
  v4f acc[16];
#pragma unroll
  for (int tl = 0; tl < 16; ++tl) {
    v4f d = __builtin_amdgcn_mfma_f32_16x16x32_f16(A0, bfr[tl][0], z, 0, 0, 0);
    acc[tl] = __builtin_amdgcn_mfma_f32_16x16x32_f16(A1, bfr[tl][1], d, 0, 0, 0);
  }
#pragma unroll
  for (int g = 0; g < 4; ++g) {
    float v01 = s0 ? acc[4 * g + 1][0] : acc[4 * g + 0][0];
    float v23 = s0 ? acc[4 * g + 3][0] : acc[4 * g + 2][0];
    p[g] = s1 ? v23 : v01;
  }
}

__global__ __attribute__((amdgpu_flat_work_group_size(512, 512),
                          amdgpu_waves_per_eu(2, 2)))
void lstm_pipe_k(
    const float* __restrict__ x,
    const float* __restrict__ wih_a0, const float* __restrict__ whh_a0,
    const float* __restrict__ bih_a0, const float* __restrict__ bhh_a0,
    const float* __restrict__ wih_a1, const float* __restrict__ whh_a1,
    const float* __restrict__ bih_a1, const float* __restrict__ bhh_a1,
    const float* __restrict__ wih_a2, const float* __restrict__ whh_a2,
    const float* __restrict__ bih_a2, const float* __restrict__ bhh_a2,
    const float* __restrict__ wih_b0, const float* __restrict__ whh_b0,
    const float* __restrict__ bih_b0, const float* __restrict__ bhh_b0,
    const float* __restrict__ wih_b1, const float* __restrict__ whh_b1,
    const float* __restrict__ bih_b1, const float* __restrict__ bhh_b1,
    const float* __restrict__ wih_b2, const float* __restrict__ whh_b2,
    const float* __restrict__ bih_b2, const float* __restrict__ bhh_b2,
    float* __restrict__ out)  // [B,T]
{
  const int b = blockIdx.x;
  const int tid = threadIdx.x;
  const int wave = tid >> 6;
  const int lane = tid & 63;

  __shared__ __align__(16) _Float16 hh[3][NS][HP];  // h rings (padded rows)
  __shared__ __align__(16) float pj[2][NS][PP];     // proj rings (padded rows)
  __shared__ float xs[TT];
  __shared__ int prog[8];                           // per-wave windows done

  for (int i = tid; i < TT; i += 512) xs[i] = x[(size_t)b * TT + i];
  for (int i = tid; i < 3 * NS * HP / 2; i += 512) reinterpret_cast<int*>(hh)[i] = 0;
  if (tid < 8) prog[tid] = 0;

  union UW {
    v8h bfr[16][2];
    v2h wtb[2][16];
  } u;

  float bias[4] = {0.f, 0.f, 0.f, 0.f};
  float wi0_[4] = {0.f, 0.f, 0.f, 0.f};
  float whb0[4] = {}, wi1b[4] = {}, wh1b[4] = {}, bb1[4] = {},
        wi2b[4] = {}, wh2b[4] = {}, bb2[4] = {};

  if (wave == 0) {  // a0 rec: B = whh_a0 fragments (SIMD0)
#pragma unroll
    for (int t = 0; t < 16; ++t) {
      u.bfr[t][0] = ldbfrag_(whh_a0, t, 0, lane);
      u.bfr[t][1] = ldbfrag_(whh_a0, t, 1, lane);
    }
#pragma unroll
    for (int q = 0; q < 4; ++q) {
      const int row = q * 64 + lane;
      bias[q] = bih_a0[row] + bhh_a0[row];
      wi0_[q] = wih_a0[row];
    }
  } else if (wave == 1) {  // a1 rec (SIMD1)
#pragma unroll
    for (int t = 0; t < 16; ++t) {
      u.bfr[t][0] = ldbfrag_(whh_a1, t, 0, lane);
      u.bfr[t][1] = ldbfrag_(whh_a1, t, 1, lane);
    }
#pragma unroll
    for (int q = 0; q < 4; ++q) bias[q] = bih_a1[q * 64 + lane] + bhh_a1[q * 64 + lane];
  } else if (wave == 2) {  // a2 rec (SIMD2)
#pragma unroll
    for (int t = 0; t < 16; ++t) {
      u.bfr[t][0] = ldbfrag_(whh_a2, t, 0, lane);
      u.bfr[t][1] = ldbfrag_(whh_a2, t, 1, lane);
    }
#pragma unroll
    for (int q = 0; q < 4; ++q) bias[q] = bih_a2[q * 64 + lane] + bhh_a2[q * 64 + lane];
  } else if (wave == 3) {  // b-chain (SIMD3)
    const int q = lane & 3;
    load_row_pair(wih_b0 + q * 64, u.wtb[0], u.wtb[1]);
    bias[0] = bih_b0[q] + bhh_b0[q];
#pragma unroll
    for (int k = 0; k < 4; ++k) {
      whb0[k] = whh_b0[k];
      wi1b[k] = wih_b1[k]; wh1b[k] = whh_b1[k]; bb1[k] = bih_b1[k] + bhh_b1[k];
      wi2b[k] = wih_b2[k]; wh2b[k] = whh_b2[k]; bb2[k] = bih_b2[k] + bhh_b2[k];
    }
    PIN16(u.wtb[0]); PIN16(u.wtb[1]);
  } else if (wave == 6) {  // a2 proj MFMA: W = wih_a2 (SIMD2)
#pragma unroll
    for (int t = 0; t < 16; ++t) {
      u.bfr[t][0] = ldbfrag_(wih_a2, t, 0, lane);
      u.bfr[t][1] = ldbfrag_(wih_a2, t, 1, lane);
    }
  } else if (wave == 7) {  // a1 proj MFMA: W = wih_a1 (SIMD3)
#pragma unroll
    for (int t = 0; t < 16; ++t) {
      u.bfr[t][0] = ldbfrag_(wih_a1, t, 0, lane);
      u.bfr[t][1] = ldbfrag_(wih_a1, t, 1, lane);
    }
  }
  __syncthreads();
  if (wave == 4 || wave == 5) return;  // no later barriers -> safe early exit

  float c = 0.f;
  float h0b = 0.f, c0b = 0.f, h1b = 0.f, c1b = 0.f, h2b = 0.f, c2b = 0.f;
  const int q4 = lane >> 4;
  const bool s0 = q4 & 1, s1 = q4 & 2;
  const v4f z = {0.f, 0.f, 0.f, 0.f};

  if (wave == 0) {  // a0 rec -> hh[0]; consumer w7
    __builtin_amdgcn_s_setprio(1);
    for (int k = 0; k < NW; ++k) {
      if (k >= 4) { WAITP(7, k - 3); }
      const int t0 = k * CH;
      for (int s = 0; s < CH; ++s) {
        const int t = t0 + s;
        v8h A0, A1;
        ldafrag_(&hh[0][(t + NS - 1) & (NS - 1)][0], q4, A0, A1);
        float p[4];
        rec_mv_(u.bfr, A0, A1, s0, s1, p);
        const float xv = xs[t];
        float p0 = __builtin_fmaf(wi0_[0], xv, p[0] + bias[0]);
        float p1 = __builtin_fmaf(wi0_[1], xv, p[1] + bias[1]);
        float p2 = __builtin_fmaf(wi0_[2], xv, p[2] + bias[2]);
        float p3 = __builtin_fmaf(wi0_[3], xv, p[3] + bias[3]);
        float gi = sig_(p0), gf = sig_(p1), gg = tanh_(p2), go = sig_(p3);
        c = __builtin_fmaf(gf, c, gi * gg);
        hh[0][t & (NS - 1)][lane] = (_Float16)(go * tanh_(c));
      }
      POSTP(0, k + 1);
    }
    __builtin_amdgcn_s_setprio(0);
  } else if (wave == 1) {  // a1 rec: reads pj[0]; -> hh[1]; consumer w6
    __builtin_amdgcn_s_setprio(1);
    for (int k = 0; k < NW; ++k) {
      WAITP(7, k + 1);
      if (k >= 4) { WAITP(6, k - 3); }
      const int t0 = k * CH;
      float4 pr = *reinterpret_cast<const float4*>(&pj[0][t0 & (NS - 1)][lane * 4]);
      for (int s = 0; s < CH; ++s) {
        const int t = t0 + s;
        v8h A0, A1;
        ldafrag_(&hh[1][(t + NS - 1) & (NS - 1)][0], q4, A0, A1);
        float4 prn = pr;
        if (s + 1 < CH)
          prn = *reinterpret_cast<const float4*>(&pj[0][(t + 1) & (NS - 1)][lane * 4]);
        float p[4];
        rec_mv_(u.bfr, A0, A1, s0, s1, p);
        float p0 = p[0] + bias[0] + pr.x;
        float p1 = p[1] + bias[1] + pr.y;
        float p2 = p[2] + bias[2] + pr.z;
        float p3 = p[3] + bias[3] + pr.w;
        float gi = sig_(p0), gf = sig_(p1), gg = tanh_(p2), go = sig_(p3);
        c = __builtin_fmaf(gf, c, gi * gg);
        hh[1][t & (NS - 1)][lane] = (_Float16)(go * tanh_(c));
        pr = prn;
      }
      POSTP(1, k + 1);
    }
    __builtin_amdgcn_s_setprio(0);
  } else if (wave == 2) {  // a2 rec: reads pj[1]; -> hh[2]; consumer w3
    __builtin_amdgcn_s_setprio(1);
    for (int k = 0; k < NW; ++k) {
      WAITP(6, k + 1);
      if (k >= 4) { WAITP(3, k - 3); }
      const int t0 = k * CH;
      float4 pr = *reinterpret_cast<const float4*>(&pj[1][t0 & (NS - 1)][lane * 4]);
      for (int s = 0; s < CH; ++s) {
        const int t = t0 + s;
        v8h A0, A1;
        ldafrag_(&hh[2][(t + NS - 1) & (NS - 1)][0], q4, A0, A1);
        float4 prn = pr;
        if (s + 1 < CH)
          prn = *reinterpret_cast<const float4*>(&pj[1][(t + 1) & (NS - 1)][lane * 4]);
        float p[4];
        rec_mv_(u.bfr, A0, A1, s0, s1, p);
        float p0 = p[0] + bias[0] + pr.x;
        float p1 = p[1] + bias[1] + pr.y;
        float p2 = p[2] + bias[2] + pr.z;
        float p3 = p[3] + bias[3] + pr.w;
        float gi = sig_(p0), gf = sig_(p1), gg = tanh_(p2), go = sig_(p3);
        c = __builtin_fmaf(gf, c, gi * gg);
        hh[2][t & (NS - 1)][lane] = (_Float16)(go * tanh_(c));
        pr = prn;
      }
      POSTP(2, k + 1);
    }
    __builtin_amdgcn_s_setprio(0);
  } else if (wave == 3) {  // b-chain: reads hh[2]
    for (int k = 0; k < NW; ++k) {
      WAITP(2, k + 1);
      const int t0 = k * CH;
      for (int s = 0; s < CH; ++s) {
        const int t = t0 + s;
        v2h hv[32];
        load_h64(&hh[2][t & (NS - 1)][0], hv);
        float pga = bias[0], pgb = 0.f;
#pragma unroll
        for (int j = 0; j < 16; ++j) {
          FDOT2(pga, u.wtb[0][j], hv[j]);
          FDOT2(pgb, u.wtb[1][j], hv[16 + j]);
        }
        float pg = pga + pgb;
        float p_i = qb_<0>(pg), p_f = qb_<1>(pg), p_g = qb_<2>(pg), p_o = qb_<3>(pg);
        float i0 = sig_(__builtin_fmaf(whb0[0], h0b, p_i));
        float f0 = sig_(__builtin_fmaf(whb0[1], h0b, p_f));
        float g0 = tanh_(__builtin_fmaf(whb0[2], h0b, p_g));
        float o0 = sig_(__builtin_fmaf(whb0[3], h0b, p_o));
        c0b = __builtin_fmaf(f0, c0b, i0 * g0);
        h0b = o0 * tanh_(c0b);
        float i1 = sig_(bb1[0] + __builtin_fmaf(wi1b[0], h0b, wh1b[0] * h1b));
        float f1 = sig_(bb1[1] + __builtin_fmaf(wi1b[1], h0b, wh1b[1] * h1b));
        float g1 = tanh_(bb1[2] + __builtin_fmaf(wi1b[2], h0b, wh1b[2] * h1b));
        float o1 = sig_(bb1[3] + __builtin_fmaf(wi1b[3], h0b, wh1b[3] * h1b));
        c1b = __builtin_fmaf(f1, c1b, i1 * g1);
        h1b = o1 * tanh_(c1b);
        float i2 = sig_(bb2[0] + __builtin_fmaf(wi2b[0], h1b, wh2b[0] * h2b));
        float f2 = sig_(bb2[1] + __builtin_fmaf(wi2b[1], h1b, wh2b[1] * h2b));
        float g2 = tanh_(bb2[2] + __builtin_fmaf(wi2b[2], h1b, wh2b[2] * h2b));
        float o2 = sig_(bb2[3] + __builtin_fmaf(wi2b[3], h1b, wh2b[3] * h2b));
        c2b = __builtin_fmaf(f2, c2b, i2 * g2);
        h2b = o2 * tanh_(c2b);
        if (lane == 0) out[(size_t)b * TT + t] = h2b;
      }
      POSTP(3, k + 1);
    }
  } else if (wave == 7) {  // a1 proj MFMA (SIMD3): hh[0] window k -> pj[0]
    for (int k = 0; k < NW; ++k) {
      WAITP(0, k + 1);
      if (k >= 4) { WAITP(1, k - 3); }
      const int t0 = k * CH;
      const int slotb = (t0 + (lane & 15)) & (NS - 1);
      v8h Bf0, Bf1;
      ldafrag_(&hh[0][slotb][0], q4, Bf0, Bf1);
      float* pbase = &pj[0][slotb][0] + 16 * q4;
      const bool wr = (lane & 15) < CH;
#pragma unroll
      for (int tl = 0; tl < 16; ++tl) {
        v4f acc = __builtin_amdgcn_mfma_f32_16x16x32_f16(u.bfr[tl][0], Bf0, z, 0, 0, 0);
        acc = __builtin_amdgcn_mfma_f32_16x16x32_f16(u.bfr[tl][1], Bf1, acc, 0, 0, 0);
        if (wr) {
          const int o = 64 * (tl & 3) + (tl >> 2);
          pbase[o] = acc[0]; pbase[o + 4] = acc[1];
          pbase[o + 8] = acc[2]; pbase[o + 12] = acc[3];
        }
        __builtin_amdgcn_sched_barrier(0);
      }
      POSTP(7, k + 1);
    }
  } else {                 // wave 6: a2 proj MFMA (SIMD2): hh[1] -> pj[1]
    for (int k = 0; k < NW; ++k) {
      WAITP(1, k + 1);
      if (k >= 4) { WAITP(2, k - 3); }
      const int t0 = k * CH;
      const int slotb = (t0 + (lane & 15)) & (NS - 1);
      v8h Bf0, Bf1;
      ldafrag_(&hh[1][slotb][0], q4, Bf0, Bf1);
      float* pbase = &pj[1][slotb][0] + 16 * q4;
      const bool wr = (lane & 15) < CH;
#pragma unroll
      for (int tl = 0; tl < 16; ++tl) {
        v4f acc = __builtin_amdgcn_mfma_f32_16x16x32_f16(u.bfr[tl][0], Bf0, z, 0, 0, 0);
        acc = __builtin_amdgcn_mfma_f32_16x16x32_f16(u.bfr[tl][1], Bf1, acc, 0, 0, 0);
        if (wr) {
          const int o = 64 * (tl & 3) + (tl >> 2);
          pbase[o] = acc[0]; pbase[o + 4] = acc[1];
          pbase[o + 8] = acc[2]; pbase[o + 12] = acc[3];
        }
        __builtin_amdgcn_sched_barrier(0);
      }
      POSTP(6, k + 1);
    }
  }
}

extern "C" void kernel_launch(void* const* d_in, const int* in_sizes, int n_in,
                              void* d_out, int out_size, void* d_ws, size_t ws_size,
                              hipStream_t stream) {
  const float* x      = (const float*)d_in[0];
  const float* wih_a0 = (const float*)d_in[1];
  const float* whh_a0 = (const float*)d_in[2];
  const float* bih_a0 = (const float*)d_in[3];
  const float* bhh_a0 = (const float*)d_in[4];
  const float* wih_a1 = (const float*)d_in[5];
  const float* whh_a1 = (const float*)d_in[6];
  const float* bih_a1 = (const float*)d_in[7];
  const float* bhh_a1 = (const float*)d_in[8];
  const float* wih_a2 = (const float*)d_in[9];
  const float* whh_a2 = (const float*)d_in[10];
  const float* bih_a2 = (const float*)d_in[11];
  const float* bhh_a2 = (const float*)d_in[12];
  const float* wih_b0 = (const float*)d_in[13];
  const float* whh_b0 = (const float*)d_in[14];
  const float* bih_b0 = (const float*)d_in[15];
  const float* bhh_b0 = (const float*)d_in[16];
  const float* wih_b1 = (const float*)d_in[17];
  const float* whh_b1 = (const float*)d_in[18];
  const float* bih_b1 = (const float*)d_in[19];
  const float* bhh_b1 = (const float*)d_in[20];
  const float* wih_b2 = (const float*)d_in[21];
  const float* whh_b2 = (const float*)d_in[22];
  const float* bih_b2 = (const float*)d_in[23];
  const float* bhh_b2 = (const float*)d_in[24];
  float* out = (float*)d_out;

  lstm_pipe_k<<<BB, 512, 0, stream>>>(
      x,
      wih_a0, whh_a0, bih_a0, bhh_a0,
      wih_a1, whh_a1, bih_a1, bhh_a1,
      wih_a2, whh_a2, bih_a2, bhh_a2,
      wih_b0, whh_b0, bih_b0, bhh_b0,
      wih_b1, whh_b1, bih_b1, bhh_b1,
      wih_b2, whh_b2, bih_b2, bhh_b2,
      out);
}